// Round 13
// baseline (76.300 us; speedup 1.0000x reference)
//
#include <hip/hip_runtime.h>
#include <hip/hip_bf16.h>

// HeteroLinear: out[b,n,o] = sum_i x[b,n,i] * W[t[n]][o][i] + bias[t[n]][o]
// B=16, N=16384, F_IN=F_OUT=128, NUM_TYPES=16, fp32 in/out.
//
// Round 13: R12's unsorted-streaming structure with the wconv coverage bug
// fixed: wbf has 32768 chunks (16t x 4kk x 8ot x 64lane); R12 launched only
// 16384 threads x 1 chunk -> types 8-15 read poison (absmax 3.39). Now 128
// blocks cover all chunks. Structure: no sort, no LDS, no syncthreads,
// 2 launches; nodes in natural order (x/out perfectly streamed); W bf16
// fragments read from L2 (512KB, L2-resident) with ping-pong prefetch.

#define NN 16384
#define FF 128
#define NT 16

typedef __bf16 bf16x8 __attribute__((ext_vector_type(8)));
typedef float  f32x4  __attribute__((ext_vector_type(4)));

// wbf chunk index c = ((t*4 + kk)*8 + ot)*64 + lane, 16B per chunk:
// holds bf16 of W[t][ot*16 + (lane&15)][kk*32 + (lane>>4)*8 + j], j=0..7.

__global__ __launch_bounds__(256) void hl_wconv(const float* __restrict__ W,
                                                unsigned char* __restrict__ wbf) {
    const int c    = blockIdx.x * 256 + threadIdx.x;   // 32768 chunks
    const int lrow = c & 15;
    const int lgrp = (c >> 4) & 3;
    const int ot   = (c >> 6) & 7;
    const int kk   = (c >> 9) & 3;
    const int t    = c >> 11;
    const float* p = W + t * (FF * FF) + (ot * 16 + lrow) * FF + kk * 32 + lgrp * 8;
    f32x4 a = *(const f32x4*)p;
    f32x4 b = *(const f32x4*)(p + 4);
    bf16x8 v;
#pragma unroll
    for (int j = 0; j < 4; ++j) { v[j] = (__bf16)a[j]; v[4 + j] = (__bf16)b[j]; }
    *(bf16x8*)(wbf + (size_t)c * 16) = v;
}

__global__ __launch_bounds__(256) void hl_main(
    const float* __restrict__ x,              // [16][NN][128]
    const int*   __restrict__ tv,             // [NN]
    const unsigned char* __restrict__ wbf,    // fragment-native bf16 W
    const float* __restrict__ bias,           // [16][128]
    float*       __restrict__ out)            // [16][NN][128]
{
    const int lane = threadIdx.x & 63;
    const int wv   = threadIdx.x >> 6;        // 0..3
    const int n    = blockIdx.x * 4 + wv;     // natural order: streamed x/out

    const int lrow = lane & 15;   // A row (b) / B col (o) / D col (o)
    const int lgrp = lane >> 4;   // k-group of 8 / D row-group

    // x loads issue immediately (independent of t)
    const float* xp0 = x + (size_t)lrow * ((size_t)NN * FF) + (size_t)n * FF + lgrp * 8;
    f32x4 xv[8];
#pragma unroll
    for (int kk = 0; kk < 4; ++kk) {
        xv[2 * kk]     = *(const f32x4*)(xp0 + kk * 32);
        xv[2 * kk + 1] = *(const f32x4*)(xp0 + kk * 32 + 4);
    }

    const int t = tv[n];
    // per-wave fragment base; fragment (kk,ot) at wb + (kk*8+ot)*1024
    const unsigned char* wb = wbf + ((size_t)t * 2048 + lane) * 16;

    // prefetch kk=0 fragments (8 x 1KB coalesced L2 reads)
    bf16x8 wfA[8], wfB[8];
#pragma unroll
    for (int ot = 0; ot < 8; ++ot) wfA[ot] = *(const bf16x8*)(wb + ot * 1024);

    float bv[8];
#pragma unroll
    for (int ot = 0; ot < 8; ++ot) bv[ot] = bias[t * FF + ot * 16 + lrow];

    // convert x to hi/lo bf16 (consumes xv)
    bf16x8 ahi[4], alo[4];
#pragma unroll
    for (int kk = 0; kk < 4; ++kk) {
#pragma unroll
        for (int j = 0; j < 4; ++j) {
            const float f0 = xv[2 * kk][j], f1 = xv[2 * kk + 1][j];
            const __bf16 h0 = (__bf16)f0, h1 = (__bf16)f1;
            ahi[kk][j]     = h0;  alo[kk][j]     = (__bf16)(f0 - (float)h0);
            ahi[kk][4 + j] = h1;  alo[kk][4 + j] = (__bf16)(f1 - (float)h1);
        }
    }

    f32x4 acc[8];
#pragma unroll
    for (int ot = 0; ot < 8; ++ot) acc[ot] = (f32x4){0.f, 0.f, 0.f, 0.f};

    // ---- kk=0: prefetch kk=1 -> wfB, compute wfA ----
#pragma unroll
    for (int ot = 0; ot < 8; ++ot) wfB[ot] = *(const bf16x8*)(wb + (8 + ot) * 1024);
    __builtin_amdgcn_sched_barrier(0);
#pragma unroll
    for (int ot = 0; ot < 8; ++ot) {
        acc[ot] = __builtin_amdgcn_mfma_f32_16x16x32_bf16(ahi[0], wfA[ot], acc[ot], 0, 0, 0);
        acc[ot] = __builtin_amdgcn_mfma_f32_16x16x32_bf16(alo[0], wfA[ot], acc[ot], 0, 0, 0);
    }
    // ---- kk=1: prefetch kk=2 -> wfA, compute wfB ----
#pragma unroll
    for (int ot = 0; ot < 8; ++ot) wfA[ot] = *(const bf16x8*)(wb + (16 + ot) * 1024);
    __builtin_amdgcn_sched_barrier(0);
#pragma unroll
    for (int ot = 0; ot < 8; ++ot) {
        acc[ot] = __builtin_amdgcn_mfma_f32_16x16x32_bf16(ahi[1], wfB[ot], acc[ot], 0, 0, 0);
        acc[ot] = __builtin_amdgcn_mfma_f32_16x16x32_bf16(alo[1], wfB[ot], acc[ot], 0, 0, 0);
    }
    // ---- kk=2: prefetch kk=3 -> wfB, compute wfA ----
#pragma unroll
    for (int ot = 0; ot < 8; ++ot) wfB[ot] = *(const bf16x8*)(wb + (24 + ot) * 1024);
    __builtin_amdgcn_sched_barrier(0);
#pragma unroll
    for (int ot = 0; ot < 8; ++ot) {
        acc[ot] = __builtin_amdgcn_mfma_f32_16x16x32_bf16(ahi[2], wfA[ot], acc[ot], 0, 0, 0);
        acc[ot] = __builtin_amdgcn_mfma_f32_16x16x32_bf16(alo[2], wfA[ot], acc[ot], 0, 0, 0);
    }
    // ---- kk=3: compute wfB ----
#pragma unroll
    for (int ot = 0; ot < 8; ++ot) {
        acc[ot] = __builtin_amdgcn_mfma_f32_16x16x32_bf16(ahi[3], wfB[ot], acc[ot], 0, 0, 0);
        acc[ot] = __builtin_amdgcn_mfma_f32_16x16x32_bf16(alo[3], wfB[ot], acc[ot], 0, 0, 0);
    }

#pragma unroll
    for (int ot = 0; ot < 8; ++ot) {
        const int o = ot * 16 + lrow;
#pragma unroll
        for (int r = 0; r < 4; ++r) {
            out[(size_t)(lgrp * 4 + r) * ((size_t)NN * FF) + (size_t)n * FF + o]
                = acc[ot][r] + bv[ot];
        }
    }
}

extern "C" void kernel_launch(void* const* d_in, const int* in_sizes, int n_in,
                              void* d_out, int out_size, void* d_ws, size_t ws_size,
                              hipStream_t stream) {
    const float* x    = (const float*)d_in[0];
    const int*   tv   = (const int*)d_in[1];
    const float* W    = (const float*)d_in[2];
    const float* bias = (const float*)d_in[3];
    float*       out  = (float*)d_out;
    unsigned char* wbf = (unsigned char*)d_ws;   // 512KB fragment image

    hl_wconv<<<128, 256, 0, stream>>>(W, wbf);
    hl_main<<<NN / 4, 256, 0, stream>>>(x, tv, wbf, bias, out);
}

// Round 14
// 67.494 us; speedup vs baseline: 1.1305x; 1.1305x over previous
//
#include <hip/hip_runtime.h>
#include <hip/hip_bf16.h>

// HeteroLinear: out[b,n,o] = sum_i x[b,n,i] * W[t[n]][o][i] + bias[t[n]][o]
// B=16, N=16384, F_IN=F_OUT=128, NUM_TYPES=16, fp32 in/out.
//
// Round 14: restore Round 11 verbatim — the best measured configuration
// (65.6us). R13's independent unsorted-streaming structure converged at
// the same ~55-60us real-main wall (76.3us total, worse prep amortization),
// confirming R11's sorted structure + pre-converted/pre-swizzled W staging
// via global_load_lds is the winner. R4 geometry: NPB=8, 2064 blocks.

#define NN 16384
#define FF 128
#define NT 16
#define NPB 8            // nodes per main block (8 waves x 1 node)
#define NBLK (NN / NPB + NT)          // 2064
#define PB 64            // prep blocks
#define WS_PORD 64
#define WS_BH (WS_PORD + NBLK * NPB)  // hist region (ints)
#define WBF_BYTE_OFF 73728            // byte offset of bf16 W images
#define WBF_BYTES (NT * FF * FF * 2)  // 512KB

typedef __bf16 bf16x8 __attribute__((ext_vector_type(8)));
typedef float  f32x4  __attribute__((ext_vector_type(4)));

// ws int layout: [48]=#real blocks; [WS_PORD..) packed node table
// (t<<20 | invalid<<16 | n); [WS_BH..) per-(type,block) hist.
// ws byte layout: [WBF_BYTE_OFF..) pre-swizzled bf16 W[t] LDS images.

__global__ __launch_bounds__(256) void hl_hist(const int* __restrict__ tv,
                                               int* __restrict__ ws,
                                               const float* __restrict__ W,
                                               unsigned char* __restrict__ wbf,
                                               int do_conv) {
    __shared__ int wh[4][NT];
    const int tid = threadIdx.x, lane = tid & 63, wv = tid >> 6;
    const int t = tv[blockIdx.x * 256 + tid];
#pragma unroll
    for (int ty = 0; ty < NT; ++ty) {
        const unsigned long long m = __ballot(t == ty);
        if (lane == 0) wh[wv][ty] = __popcll(m);
    }
    __syncthreads();
    if (tid < NT)
        ws[WS_BH + tid * PB + blockIdx.x] = wh[0][tid] + wh[1][tid] + wh[2][tid] + wh[3][tid];

    if (do_conv) {
        // 32768 chunks of 8 floats; 16384 threads -> 2 chunks each.
#pragma unroll
        for (int c = 0; c < 2; ++c) {
            const int idx = c * 16384 + blockIdx.x * 256 + tid;
            const int ty  = idx >> 11;          // 2048 chunks per type
            const int id  = idx & 2047;
            const int o   = id >> 4;            // W row
            const int kb  = (id & 15) << 4;     // byte col within 256B row
            const float* p = W + ty * (FF * FF) + o * FF + (id & 15) * 8;
            f32x4 a = *(const f32x4*)p;
            f32x4 b = *(const f32x4*)(p + 4);
            bf16x8 v;
#pragma unroll
            for (int j = 0; j < 4; ++j) { v[j] = (__bf16)a[j]; v[4 + j] = (__bf16)b[j]; }
            *(bf16x8*)(wbf + ty * 32768 + o * 256 + (kb ^ ((o & 7) << 4))) = v;
        }
    }
}

__global__ __launch_bounds__(256) void hl_scatter(const int* __restrict__ tv,
                                                  int* __restrict__ ws) {
    __shared__ int bh[NT * PB];
    __shared__ int scnt[NT], mybase[NT], sblk[NT + 1];
    __shared__ int wh[4][NT], wbase[4][NT];
    const int tid = threadIdx.x, lane = tid & 63, wv = tid >> 6;

    for (int i = tid; i < NT * PB; i += 256) bh[i] = ws[WS_BH + i];

    const int n = blockIdx.x * 256 + tid;
    const int t = tv[n];
    int myrank = 0;
#pragma unroll
    for (int ty = 0; ty < NT; ++ty) {
        const unsigned long long m = __ballot(t == ty);
        if (lane == 0) wh[wv][ty] = __popcll(m);
        if (t == ty) myrank = __popcll(m & ((1ull << lane) - 1ull));
    }
    __syncthreads();
    if (tid < NT) {                 // per-type: global count + my block's base
        int acc = 0, myb = 0;
        for (int b = 0; b < PB; ++b) {
            if (b == (int)blockIdx.x) myb = acc;
            acc += bh[tid * PB + b];
        }
        scnt[tid] = acc;
        mybase[tid] = myb;
    }
    __syncthreads();
    if (tid == 0) {                 // padded block offsets per type
        int bacc = 0;
        for (int ty = 0; ty < NT; ++ty) {
            sblk[ty] = bacc;
            bacc += (scnt[ty] + NPB - 1) / NPB;
        }
        sblk[NT] = bacc;
        if (blockIdx.x == 0) ws[48] = bacc;
    }
    __syncthreads();
    if (tid < NT) {
        int base = sblk[tid] * NPB + mybase[tid];
        for (int w = 0; w < 4; ++w) { wbase[w][tid] = base; base += wh[w][tid]; }
    }
    __syncthreads();
    ws[WS_PORD + wbase[wv][t] + myrank] = (t << 20) | n;     // valid entry

    if (blockIdx.x == 0 && tid < NT) {                       // typed sentinels
        const int lo = sblk[tid] * NPB + scnt[tid];
        const int hi = sblk[tid + 1] * NPB;
        for (int s = lo; s < hi; ++s) ws[WS_PORD + s] = (tid << 20) | 0x10000;
    }
}

template <int PRE>
__global__ __launch_bounds__(512, 4) void hl_main(
    const float* __restrict__ x,              // [16][NN][128]
    const float* __restrict__ W,              // [16][128][128]
    const unsigned char* __restrict__ wbf,    // pre-swizzled bf16 W images
    const float* __restrict__ bias,           // [16][128]
    const int*   __restrict__ ws,
    float*       __restrict__ out)            // [16][NN][128]
{
    const int lane = threadIdx.x & 63;
    const int wv   = threadIdx.x >> 6;   // 0..7 = node slot
    const int bid  = blockIdx.x;

    const int e0 = ws[WS_PORD + bid * NPB + wv];
    if (bid >= ws[48]) return;

    const int  t  = e0 >> 20;
    const bool v0 = !(e0 & 0x10000);
    const int  n0 = e0 & 0x3FFF;

    const int lrow = lane & 15;   // A row (b) / B col (o) / D col (o)
    const int lgrp = lane >> 4;   // k-group of 8 / D row-group

    // x loads in flight under W staging
    const float* xbase = x + (size_t)lrow * ((size_t)NN * FF) + lgrp * 8;
    f32x4 xv[8];
#pragma unroll
    for (int kk = 0; kk < 4; ++kk) {
        const float* xp = xbase + (size_t)n0 * FF + kk * 32;
        xv[2 * kk]     = *(const f32x4*)xp;
        xv[2 * kk + 1] = *(const f32x4*)(xp + 4);
    }

    float bv[8];
#pragma unroll
    for (int ot = 0; ot < 8; ++ot) bv[ot] = bias[t * FF + ot * 16 + lrow];

    // stage W[t]: LDS image is pre-built -> pure linear copy
    __shared__ __align__(16) unsigned char Wl[FF * 256];
    if constexpr (PRE) {
#if __has_builtin(__builtin_amdgcn_global_load_lds)
        const unsigned char* wsrc = wbf + t * 32768 + wv * 4096 + lane * 16;
#pragma unroll
        for (int j = 0; j < 4; ++j) {
            __builtin_amdgcn_global_load_lds(
                (const __attribute__((address_space(1))) unsigned int*)(wsrc + j * 1024),
                (__attribute__((address_space(3))) unsigned int*)(Wl + wv * 4096 + j * 1024),
                16, 0, 0);
        }
#else
#pragma unroll
        for (int ii = 0; ii < 4; ++ii) {
            const int idx = ii * 512 + threadIdx.x;
            *(bf16x8*)(Wl + idx * 16) = *(const bf16x8*)(wbf + t * 32768 + idx * 16);
        }
#endif
    } else {
        const float* Wt = W + t * (FF * FF);
#pragma unroll
        for (int ii = 0; ii < 4; ++ii) {
            const int idx = ii * 512 + threadIdx.x;
            const float* p = Wt + idx * 8;
            f32x4 a = *(const f32x4*)p;
            f32x4 b = *(const f32x4*)(p + 4);
            bf16x8 vv;
#pragma unroll
            for (int j = 0; j < 4; ++j) { vv[j] = (__bf16)a[j]; vv[4 + j] = (__bf16)b[j]; }
            const int o  = idx >> 4;
            const int cb = (idx & 15) << 4;
            *(bf16x8*)(Wl + o * 256 + (cb ^ ((o & 7) << 4))) = vv;
        }
    }
    __syncthreads();

    // convert x to hi/lo bf16 (consumes xv)
    bf16x8 ahi[4], alo[4];
#pragma unroll
    for (int kk = 0; kk < 4; ++kk) {
#pragma unroll
        for (int j = 0; j < 4; ++j) {
            const float f0 = xv[2 * kk][j], f1 = xv[2 * kk + 1][j];
            const __bf16 h0 = (__bf16)f0, h1 = (__bf16)f1;
            ahi[kk][j]     = h0;  alo[kk][j]     = (__bf16)(f0 - (float)h0);
            ahi[kk][4 + j] = h1;  alo[kk][4 + j] = (__bf16)(f1 - (float)h1);
        }
    }

    f32x4 acc[8];
#pragma unroll
    for (int ot = 0; ot < 8; ++ot) acc[ot] = (f32x4){0.f, 0.f, 0.f, 0.f};
#pragma unroll
    for (int kk = 0; kk < 4; ++kk) {
#pragma unroll
        for (int ot = 0; ot < 8; ++ot) {
            const int o  = ot * 16 + lrow;
            const int cb = (kk * 64 + lgrp * 16) ^ ((o & 7) << 4);
            const bf16x8 wf = *(const bf16x8*)(Wl + o * 256 + cb);
            acc[ot] = __builtin_amdgcn_mfma_f32_16x16x32_bf16(ahi[kk], wf, acc[ot], 0, 0, 0);
            acc[ot] = __builtin_amdgcn_mfma_f32_16x16x32_bf16(alo[kk], wf, acc[ot], 0, 0, 0);
        }
    }

    if (v0) {
#pragma unroll
        for (int ot = 0; ot < 8; ++ot) {
            const int o = ot * 16 + lrow;
#pragma unroll
            for (int r = 0; r < 4; ++r) {
                out[(size_t)(lgrp * 4 + r) * ((size_t)NN * FF) + (size_t)n0 * FF + o]
                    = acc[ot][r] + bv[ot];
            }
        }
    }
}

extern "C" void kernel_launch(void* const* d_in, const int* in_sizes, int n_in,
                              void* d_out, int out_size, void* d_ws, size_t ws_size,
                              hipStream_t stream) {
    const float* x    = (const float*)d_in[0];
    const int*   tv   = (const int*)d_in[1];
    const float* W    = (const float*)d_in[2];
    const float* bias = (const float*)d_in[3];
    float*       out  = (float*)d_out;
    int*         wsI  = (int*)d_ws;
    unsigned char* wbf = (unsigned char*)d_ws + WBF_BYTE_OFF;

    const int pre = (ws_size >= (size_t)WBF_BYTE_OFF + WBF_BYTES) ? 1 : 0;

    hl_hist<<<PB, 256, 0, stream>>>(tv, wsI, W, wbf, pre);
    hl_scatter<<<PB, 256, 0, stream>>>(tv, wsI);
    if (pre) hl_main<1><<<NBLK, 512, 0, stream>>>(x, W, wbf, bias, wsI, out);
    else     hl_main<0><<<NBLK, 512, 0, stream>>>(x, W, wbf, bias, wsI, out);
}